// Round 5
// baseline (374.104 us; speedup 1.0000x reference)
//
#include <hip/hip_runtime.h>
#include <cmath>

// ---------------------------------------------------------------------------
// Decoder_1898375544952: STGCN decoder (radix CSR + quantized fused gather+MFMA)
//   h0 = x @ W_lin + b_lin                         [N,16]
//   h3 = relu(h0 @ Ws3 + mean_agg(h0) @ Wn3 + b3)  [N,32]
//   h2 = relu(h3 @ Ws2 + mean_agg(h3) @ Wn2 + b2)  [N,64]
//   out= sigm(h2 @ Ws1 + mean_agg(h2) @ Wn1 + b1)  [N,128]
//
// R9 radix CSR -> 377us. R10 fp16 MFMA -> 339us.
// R11/R12/R13: gather MLP/chunking/phase-sort all NEUTRAL -> random-row
//   gather pinned at memory-side random ceiling; lever is BYTES per edge.
// R14: u8 global-scale quant gather: gather<64> 67->~40us BUT total 354us:
//   extra passes + NT agg stores (GEMMs re-fetch agg from HBM) ate the win;
//   partition_kernel exposed as #1 (43us, 1.5TB/s, WRITE 50MB vs 16 ideal).
// R15: (a) FUSE gather into GEMM: phase A gathers the block's 64 nodes into
//   padded LDS agg tile, one barrier, phase B MFMA reads agg from LDS ->
//   agg never touches global (saves ~56MB round-trip + 3 launches + NT bug).
//   (b) pack part entries to u32 (src<<8 | dst&255) -> halves partition
//   write + local_csr read. (c) NBLK 512->256: 64B per-bucket runs -> full
//   sectors. (d) revert R13 phase-sort (was neutral). (e) NT final fp32 out.
// ---------------------------------------------------------------------------

typedef __attribute__((ext_vector_type(8))) _Float16 half8;
typedef __attribute__((ext_vector_type(4))) float floatx4;

#define NBUCKET 512
#define BUCKET_SHIFT 8   // 256 nodes per bucket; N = 131072 = 512*256

// ---- init: zero the two scale slots (float-as-int, values >= 0) ----
__global__ void init_scales_kernel(int* __restrict__ g) { g[0] = 0; g[1] = 0; }

// ---- Pass A: per-block bucket histogram (LDS atomics only) ----
__global__ __launch_bounds__(256) void bucket_hist_kernel(
    const int* __restrict__ dst, int* __restrict__ bcnt, int E, int EPB, int nblk) {
    __shared__ int lh[NBUCKET];
    for (int i = threadIdx.x; i < NBUCKET; i += 256) lh[i] = 0;
    __syncthreads();
    int base = blockIdx.x * EPB;
    int end  = min(base + EPB, E);
    for (int i = base + threadIdx.x; i < end; i += 256)
        atomicAdd(&lh[dst[i] >> BUCKET_SHIFT], 1);
    __syncthreads();
    for (int i = threadIdx.x; i < NBUCKET; i += 256)
        bcnt[i * nblk + blockIdx.x] = lh[i];        // bucket-major
}

// ---- scan helpers ----
__global__ void scan1_kernel(const int* __restrict__ in, int* __restrict__ out,
                             int* __restrict__ bsum) {
    __shared__ int s[256];
    int i = blockIdx.x * 256 + threadIdx.x;
    int v = in[i];
    s[threadIdx.x] = v;
    __syncthreads();
    for (int off = 1; off < 256; off <<= 1) {
        int t = (threadIdx.x >= off) ? s[threadIdx.x - off] : 0;
        __syncthreads();
        s[threadIdx.x] += t;
        __syncthreads();
    }
    out[i] = s[threadIdx.x] - v;
    if (threadIdx.x == 255) bsum[blockIdx.x] = s[255];
}

__global__ void scan2_kernel(int* __restrict__ bsum, int NB) {
    extern __shared__ int s2[];
    int v = (threadIdx.x < NB) ? bsum[threadIdx.x] : 0;
    s2[threadIdx.x] = v;
    __syncthreads();
    for (int off = 1; off < NB; off <<= 1) {
        int t = (threadIdx.x >= off) ? s2[threadIdx.x - off] : 0;
        __syncthreads();
        s2[threadIdx.x] += t;
        __syncthreads();
    }
    if (threadIdx.x < NB) bsum[threadIdx.x] = s2[threadIdx.x] - v;
}

__global__ void scan3_kernel(int* __restrict__ out, const int* __restrict__ bsum) {
    int i = blockIdx.x * 256 + threadIdx.x;
    out[i] += bsum[blockIdx.x];
}

// ---- Pass C: partition edges into bucket segments (LDS cursors) ----
// Packed entry: (src << 8) | (dst & 255). src < 2^24, bucket-local dst 8b.
__global__ __launch_bounds__(256) void partition_kernel(
    const int* __restrict__ src, const int* __restrict__ dst,
    const int* __restrict__ bofs, int* __restrict__ part,
    int E, int EPB, int nblk) {
    __shared__ int cur[NBUCKET];
    for (int i = threadIdx.x; i < NBUCKET; i += 256)
        cur[i] = bofs[i * nblk + blockIdx.x];
    __syncthreads();
    int base = blockIdx.x * EPB;
    int end  = min(base + EPB, E);
    for (int i = base + threadIdx.x; i < end; i += 256) {
        int d = dst[i];
        int p = atomicAdd(&cur[d >> BUCKET_SHIFT], 1);
        part[p] = (src[i] << 8) | (d & 255);
    }
}

// ---- Pass D: per-bucket local CSR (row_ptr + csr_src), all LDS-local ----
__global__ __launch_bounds__(256) void local_csr_kernel(
    const int* __restrict__ bofs, const int* __restrict__ part,
    int* __restrict__ row_ptr, int* __restrict__ csr_src,
    int N, int E, int nblk) {
    __shared__ int cnt[256];
    __shared__ int offs[256];
    const int u      = blockIdx.x;
    const int node0  = u << BUCKET_SHIFT;
    const int bstart = bofs[(size_t)u * nblk];
    const int bend   = (u + 1 < gridDim.x) ? bofs[(size_t)(u + 1) * nblk] : E;

    cnt[threadIdx.x] = 0;
    __syncthreads();
    for (int i = bstart + threadIdx.x; i < bend; i += 256)
        atomicAdd(&cnt[part[i] & 255], 1);
    __syncthreads();

    int v = cnt[threadIdx.x];
    offs[threadIdx.x] = v;
    __syncthreads();
    for (int off = 1; off < 256; off <<= 1) {
        int t = (threadIdx.x >= off) ? offs[threadIdx.x - off] : 0;
        __syncthreads();
        offs[threadIdx.x] += t;
        __syncthreads();
    }
    int excl = offs[threadIdx.x] - v;
    int rbase = bstart + excl;
    if (node0 + threadIdx.x < N) row_ptr[node0 + threadIdx.x] = rbase;
    if (u == 0 && threadIdx.x == 0) row_ptr[N] = E;
    __syncthreads();
    cnt[threadIdx.x] = rbase;       // reuse as cursor
    __syncthreads();
    for (int i = bstart + threadIdx.x; i < bend; i += 256) {
        int e = part[i];
        int p = atomicAdd(&cnt[e & 255], 1);
        csr_src[p] = e >> 8;
    }
}

// ---- weight transpose+concat: Wt[n][k] = (k<CI ? Ws[k][n] : Wn[k-CI][n]) fp16
__global__ void wt_kernel(const float* __restrict__ Ws, const float* __restrict__ Wn,
                          _Float16* __restrict__ Wt, int CI, int NOUT) {
    int K = 2 * CI;
    int idx = blockIdx.x * 256 + threadIdx.x;
    if (idx >= NOUT * K) return;
    int n = idx / K, k = idx - n * K;
    float v = (k < CI) ? Ws[(size_t)k * NOUT + n] : Wn[(size_t)(k - CI) * NOUT + n];
    Wt[idx] = (_Float16)v;
}

// h0 = x @ W (16x16) + b, stored fp16
__global__ void lin16_kernel(const float* __restrict__ x, const float* __restrict__ W,
                             const float* __restrict__ b, _Float16* __restrict__ h, int N) {
    __shared__ float sW[256];
    __shared__ float sb[16];
    sW[threadIdx.x] = W[threadIdx.x];          // blockDim.x == 256
    if (threadIdx.x < 16) sb[threadIdx.x] = b[threadIdx.x];
    __syncthreads();
    int n = blockIdx.x * blockDim.x + threadIdx.x;
    if (n >= N) return;
    const float4* xr = (const float4*)(x + (size_t)n * 16);
    float4 x0 = xr[0], x1 = xr[1], x2 = xr[2], x3 = xr[3];
    float xi[16] = {x0.x, x0.y, x0.z, x0.w, x1.x, x1.y, x1.z, x1.w,
                    x2.x, x2.y, x2.z, x2.w, x3.x, x3.y, x3.z, x3.w};
    float o[16];
#pragma unroll
    for (int j = 0; j < 16; j++) o[j] = sb[j];
#pragma unroll
    for (int k = 0; k < 16; k++) {
        float xv = xi[k];
#pragma unroll
        for (int j = 0; j < 16; j++) o[j] += xv * sW[k * 16 + j];
    }
    half8 h0v, h1v;
#pragma unroll
    for (int j = 0; j < 8; j++) { h0v[j] = (_Float16)o[j]; h1v[j] = (_Float16)o[j + 8]; }
    half8* hr = (half8*)(h + (size_t)n * 16);
    hr[0] = h0v;
    hr[1] = h1v;
}

// ---- quantize: q[i] = round(h[i] * 255/M), h >= 0 (relu) ----
__global__ __launch_bounds__(256) void quant_kernel(
    const _Float16* __restrict__ h, const int* __restrict__ maxbits,
    unsigned char* __restrict__ q, int total16) {
    int t = blockIdx.x * 256 + threadIdx.x;
    if (t >= total16) return;
    float M = __int_as_float(*maxbits);
    float inv = (M > 1e-20f) ? 255.0f / M : 0.0f;
    const half8* hp = (const half8*)(h + (size_t)t * 16);
    half8 v0 = hp[0], v1 = hp[1];
    unsigned int dw[4] = {0u, 0u, 0u, 0u};
#pragma unroll
    for (int i = 0; i < 8; i++) {
        unsigned int b = (unsigned int)((float)v0[i] * inv + 0.5f);
        if (b > 255u) b = 255u;
        dw[i >> 2] |= b << ((i & 3) * 8);
    }
#pragma unroll
    for (int i = 0; i < 8; i++) {
        unsigned int b = (unsigned int)((float)v1[i] * inv + 0.5f);
        if (b > 255u) b = 255u;
        dw[2 + (i >> 2)] |= b << ((i & 3) * 8);
    }
    uint4 o; o.x = dw[0]; o.y = dw[1]; o.z = dw[2]; o.w = dw[3];
    *(uint4*)(q + (size_t)t * 16) = o;
}

// int-accumulate helpers for u8 gather (exact: sum <= 255*deg << 2^31)
#define ACC4(d, o)                                 \
    { unsigned int _d = (d);                        \
      a[(o)]     += _d & 0xffu;                     \
      a[(o) + 1] += (_d >> 8) & 0xffu;              \
      a[(o) + 2] += (_d >> 16) & 0xffu;             \
      a[(o) + 3] += _d >> 24; }
#define ACC4W(d, w, o)                              \
    { unsigned int _d = (d); int _w = (w);          \
      a[(o)]     += _w * (int)(_d & 0xffu);         \
      a[(o) + 1] += _w * (int)((_d >> 8) & 0xffu);  \
      a[(o) + 2] += _w * (int)((_d >> 16) & 0xffu); \
      a[(o) + 3] += _w * (int)(_d >> 24); }

// ---- FUSED gather + MFMA GEMM ----
// Grid: N/64 blocks x 256 threads. Phase A: gather the block's 64 nodes'
// mean-agg into LDS tile aggL[64][CI+8] (u8 table if QIN, else fp16 h).
// Phase B: out = act([h_self | aggL] @ Wt^T + b). agg never touches global.
// A-frag: lane m=lane&15, quad=lane>>4; k8=s*32+quad*8; k8<CI -> global
// h[row][k8..+8]; else LDS aggL[wave*16+m][k8-CI..+8]. C/D: col=c*16+m,
// row=row0+wave*16+quad*4+reg. TRACKMAX: global max via LDS+atomicMax.
template <int CI, int NOUT, int ACT, bool OUT_F16, bool TRACKMAX, bool QIN>
__global__ __launch_bounds__(256) void fused_kernel(
    const _Float16* __restrict__ hbuf, const unsigned char* __restrict__ hq,
    const int* __restrict__ row_ptr, const int* __restrict__ csr_src,
    const _Float16* __restrict__ Wt, const float* __restrict__ bias,
    const int* __restrict__ scalebits, int* __restrict__ maxbits,
    void* __restrict__ outp, int N)
{
    constexpr int K   = 2 * CI;
    constexpr int KS  = K / 32;        // k-steps (4/2/1)
    constexpr int CT  = NOUT / 16;     // col tiles (8/4/2)
    constexpr int LDW = K + 8;         // padded Bt row (halves)
    constexpr int LDA = CI + 8;        // padded agg row (halves); (CI+8)*2 %16==0
    __shared__ _Float16 Bt[NOUT * LDW];
    __shared__ _Float16 aggL[64 * LDA];
    __shared__ int smax;

    const int tid  = threadIdx.x;
    const int row0 = blockIdx.x * 64;

    // stage Wt -> LDS (issue early; completes before the single barrier)
    for (int idx = tid; idx < NOUT * (K / 8); idx += 256) {
        int n  = idx / (K / 8);
        int kq = idx - n * (K / 8);
        *(half8*)&Bt[n * LDW + kq * 8] = *(const half8*)(Wt + (size_t)n * K + kq * 8);
    }
    if (TRACKMAX && tid == 0) smax = 0;

    // ---- phase A: gather into aggL ----
    if (QIN) {
        constexpr int GP = CI / 16;            // lanes per node (16B each)
        if (tid < 64 * GP) {
            int n_l = tid / GP;
            int g   = tid % GP;
            int n   = row0 + n_l;
            const int beg = row_ptr[n];
            const int end = row_ptr[n + 1];
            const size_t goff = (size_t)g * 16;
            int a[16];
#pragma unroll
            for (int i = 0; i < 16; i++) a[i] = 0;
            int j = beg;
            for (; j + 4 <= end; j += 4) {
                int i0 = __builtin_nontemporal_load(csr_src + j + 0);
                int i1 = __builtin_nontemporal_load(csr_src + j + 1);
                int i2 = __builtin_nontemporal_load(csr_src + j + 2);
                int i3 = __builtin_nontemporal_load(csr_src + j + 3);
                uint4 q0 = *(const uint4*)(hq + (size_t)i0 * CI + goff);
                uint4 q1 = *(const uint4*)(hq + (size_t)i1 * CI + goff);
                uint4 q2 = *(const uint4*)(hq + (size_t)i2 * CI + goff);
                uint4 q3 = *(const uint4*)(hq + (size_t)i3 * CI + goff);
                ACC4(q0.x, 0) ACC4(q0.y, 4) ACC4(q0.z, 8) ACC4(q0.w, 12)
                ACC4(q1.x, 0) ACC4(q1.y, 4) ACC4(q1.z, 8) ACC4(q1.w, 12)
                ACC4(q2.x, 0) ACC4(q2.y, 4) ACC4(q2.z, 8) ACC4(q2.w, 12)
                ACC4(q3.x, 0) ACC4(q3.y, 4) ACC4(q3.z, 8) ACC4(q3.w, 12)
            }
            if (j < end) {
                const int last = end - 1;
                int i0 = csr_src[j];
                int i1 = csr_src[min(j + 1, last)];
                int i2 = csr_src[min(j + 2, last)];
                int i3 = csr_src[min(j + 3, last)];
                uint4 q0 = *(const uint4*)(hq + (size_t)i0 * CI + goff);
                uint4 q1 = *(const uint4*)(hq + (size_t)i1 * CI + goff);
                uint4 q2 = *(const uint4*)(hq + (size_t)i2 * CI + goff);
                uint4 q3 = *(const uint4*)(hq + (size_t)i3 * CI + goff);
                int w1 = (j + 1 < end) ? 1 : 0;
                int w2 = (j + 2 < end) ? 1 : 0;
                int w3 = (j + 3 < end) ? 1 : 0;
                ACC4(q0.x, 0) ACC4(q0.y, 4) ACC4(q0.z, 8) ACC4(q0.w, 12)
                ACC4W(q1.x, w1, 0) ACC4W(q1.y, w1, 4) ACC4W(q1.z, w1, 8) ACC4W(q1.w, w1, 12)
                ACC4W(q2.x, w2, 0) ACC4W(q2.y, w2, 4) ACC4W(q2.z, w2, 8) ACC4W(q2.w, w2, 12)
                ACC4W(q3.x, w3, 0) ACC4W(q3.y, w3, 4) ACC4W(q3.z, w3, 8) ACC4W(q3.w, w3, 12)
            }
            float M  = __int_as_float(*scalebits);
            float sc = (M * (1.0f / 255.0f)) / fmaxf((float)(end - beg), 1.0f);
            half8 rl, rh;
#pragma unroll
            for (int i = 0; i < 8; i++) {
                rl[i] = (_Float16)((float)a[i] * sc);
                rh[i] = (_Float16)((float)a[i + 8] * sc);
            }
            _Float16* ap = &aggL[n_l * LDA + g * 16];
            *(half8*)ap       = rl;
            *(half8*)(ap + 8) = rh;
        }
    } else {
        // fp16 path (CI == 16): one thread per node, 32B rows
        if (tid < 64) {
            int n = row0 + tid;
            const int beg = row_ptr[n];
            const int end = row_ptr[n + 1];
            float a[16];
#pragma unroll
            for (int i = 0; i < 16; i++) a[i] = 0.f;
            int j = beg;
            for (; j + 4 <= end; j += 4) {
                int i0 = __builtin_nontemporal_load(csr_src + j + 0);
                int i1 = __builtin_nontemporal_load(csr_src + j + 1);
                int i2 = __builtin_nontemporal_load(csr_src + j + 2);
                int i3 = __builtin_nontemporal_load(csr_src + j + 3);
                const half8* r0 = (const half8*)(hbuf + (size_t)i0 * 16);
                const half8* r1 = (const half8*)(hbuf + (size_t)i1 * 16);
                const half8* r2 = (const half8*)(hbuf + (size_t)i2 * 16);
                const half8* r3 = (const half8*)(hbuf + (size_t)i3 * 16);
                half8 v0l = r0[0], v0h = r0[1];
                half8 v1l = r1[0], v1h = r1[1];
                half8 v2l = r2[0], v2h = r2[1];
                half8 v3l = r3[0], v3h = r3[1];
#pragma unroll
                for (int i = 0; i < 8; i++) {
                    a[i]     += ((float)v0l[i] + (float)v1l[i]) + ((float)v2l[i] + (float)v3l[i]);
                    a[i + 8] += ((float)v0h[i] + (float)v1h[i]) + ((float)v2h[i] + (float)v3h[i]);
                }
            }
            if (j < end) {
                const int last = end - 1;
                int i0 = csr_src[j];
                int i1 = csr_src[min(j + 1, last)];
                int i2 = csr_src[min(j + 2, last)];
                int i3 = csr_src[min(j + 3, last)];
                const half8* r0 = (const half8*)(hbuf + (size_t)i0 * 16);
                const half8* r1 = (const half8*)(hbuf + (size_t)i1 * 16);
                const half8* r2 = (const half8*)(hbuf + (size_t)i2 * 16);
                const half8* r3 = (const half8*)(hbuf + (size_t)i3 * 16);
                half8 v0l = r0[0], v0h = r0[1];
                half8 v1l = r1[0], v1h = r1[1];
                half8 v2l = r2[0], v2h = r2[1];
                half8 v3l = r3[0], v3h = r3[1];
                float w1 = (j + 1 < end) ? 1.f : 0.f;
                float w2 = (j + 2 < end) ? 1.f : 0.f;
                float w3 = (j + 3 < end) ? 1.f : 0.f;
#pragma unroll
                for (int i = 0; i < 8; i++) {
                    a[i]     += ((float)v0l[i] + w1 * (float)v1l[i]) + (w2 * (float)v2l[i] + w3 * (float)v3l[i]);
                    a[i + 8] += ((float)v0h[i] + w1 * (float)v1h[i]) + (w2 * (float)v2h[i] + w3 * (float)v3h[i]);
                }
            }
            float inv = 1.0f / fmaxf((float)(end - beg), 1.0f);
            half8 rl, rh;
#pragma unroll
            for (int i = 0; i < 8; i++) {
                rl[i] = (_Float16)(a[i] * inv);
                rh[i] = (_Float16)(a[i + 8] * inv);
            }
            _Float16* ap = &aggL[tid * LDA];
            *(half8*)ap       = rl;
            *(half8*)(ap + 8) = rh;
        }
    }
    __syncthreads();

    // ---- phase B: MFMA GEMM ----
    const int wave = tid >> 6;
    const int lane = tid & 63;
    const int m    = lane & 15;
    const int quad = lane >> 4;
    const int r0w  = row0 + wave * 16;
    const size_t row = (size_t)(r0w + m);
    const int arow = wave * 16 + m;            // node-local index into aggL

    floatx4 acc[CT];
#pragma unroll
    for (int c = 0; c < CT; c++) acc[c] = (floatx4){0.f, 0.f, 0.f, 0.f};

#pragma unroll
    for (int s = 0; s < KS; s++) {
        int k8 = s * 32 + quad * 8;
        half8 a;
        if (k8 < CI) a = *(const half8*)(hbuf + row * CI + k8);
        else         a = *(const half8*)&aggL[arow * LDA + (k8 - CI)];
#pragma unroll
        for (int c = 0; c < CT; c++) {
            half8 b = *(const half8*)&Bt[(c * 16 + m) * LDW + k8];
            acc[c] = __builtin_amdgcn_mfma_f32_16x16x32_f16(a, b, acc[c], 0, 0, 0);
        }
    }

    float tmax = 0.0f;
#pragma unroll
    for (int c = 0; c < CT; c++) {
        int col = c * 16 + m;
        float bv = bias[col];
#pragma unroll
        for (int j = 0; j < 4; j++) {
            int orow = r0w + quad * 4 + j;
            float v = acc[c][j] + bv;
            if (ACT == 0) v = fmaxf(v, 0.0f);
            else          v = 1.0f / (1.0f + __expf(-v));
            if (TRACKMAX) tmax = fmaxf(tmax, v);
            if (OUT_F16) ((_Float16*)outp)[(size_t)orow * NOUT + col] = (_Float16)v;
            else __builtin_nontemporal_store(v, &((float*)outp)[(size_t)orow * NOUT + col]);
        }
    }
    if (TRACKMAX) {
        atomicMax(&smax, __float_as_int(tmax));
        __syncthreads();
        if (tid == 0) atomicMax(maxbits, smax);
    }
}

extern "C" void kernel_launch(void* const* d_in, const int* in_sizes, int n_in,
                              void* d_out, int out_size, void* d_ws, size_t ws_size,
                              hipStream_t stream) {
    const float* x     = (const float*)d_in[0];
    const int*   ei    = (const int*)d_in[1];
    // d_in[2]: batch (unused)
    const float* W_lin = (const float*)d_in[3];
    const float* b_lin = (const float*)d_in[4];
    const float* Ws3   = (const float*)d_in[5];
    const float* Wn3   = (const float*)d_in[6];
    const float* b3    = (const float*)d_in[7];
    const float* Ws2   = (const float*)d_in[8];
    const float* Wn2   = (const float*)d_in[9];
    const float* b2    = (const float*)d_in[10];
    const float* Ws1   = (const float*)d_in[11];
    const float* Wn1   = (const float*)d_in[12];
    const float* b1    = (const float*)d_in[13];
    float* out = (float*)d_out;

    const int N = in_sizes[0] / 16;
    const int E = in_sizes[1] / 2;
    const int* src = ei;
    const int* dst = ei + E;

    const int NBLK = 256;                       // partition blocks (64B runs)
    const int EPB  = (E + NBLK - 1) / NBLK;
    const int M    = NBUCKET * NBLK;            // 131072 count entries
    const int NB2  = M / 256;                   // 512

    // Workspace layout (ints unless noted).
    int* wsi = (int*)d_ws;
    int* row_ptr = wsi;
    size_t B0 = ((size_t)(N + 1) + 3) & ~(size_t)3;
    int* bcnt = wsi + B0;
    int* bofs = bcnt + M;
    int* bsum = bofs + M;
    int* gmax = bsum + NB2;                     // [0]=max(h3), [1]=max(h2)
    size_t C0 = (B0 + 2 * (size_t)M + (size_t)NB2 + 2 + 3) & ~(size_t)3;
    int* csr_src = wsi + C0;
    size_t P0 = (C0 + (size_t)E + 3) & ~(size_t)3;
    int* part = wsi + P0;                       // E packed u32; dead after local_csr
    size_t H0 = (P0 + 2 * (size_t)E + 3) & ~(size_t)3;   // keep 2E reservation
    _Float16* regA = (_Float16*)(wsi + H0);
    _Float16* regB = regA + (size_t)64 * N;
    _Float16* Wt1  = regB + (size_t)64 * N;     // 128*128 = 16384 halves
    _Float16* Wt2  = Wt1 + 16384;               // 64*64   = 4096
    _Float16* Wt3  = Wt2 + 4096;                // 32*32   = 1024

    _Float16* h0    = regA;
    _Float16* h2    = regA + (size_t)16 * N;   // after h0 only (agg now in LDS)
    _Float16* h3    = regB;

    // quantized tables overlay part's 2E-int reservation (part dead by then)
    unsigned char* h3q = (unsigned char*)part;                   // N*32 B
    unsigned char* h2q = (unsigned char*)part + (size_t)32 * N;  // N*64 B

    const int BLK = 256;

    // ---- init scale slots ----
    init_scales_kernel<<<1, 1, 0, stream>>>(gmax);

    // ---- weight transposes (tiny) ----
    wt_kernel<<<(32 * 32 + 255) / 256, 256, 0, stream>>>(Ws3, Wn3, Wt3, 16, 32);
    wt_kernel<<<(64 * 64 + 255) / 256, 256, 0, stream>>>(Ws2, Wn2, Wt2, 32, 64);
    wt_kernel<<<(128 * 128 + 255) / 256, 256, 0, stream>>>(Ws1, Wn1, Wt1, 64, 128);

    // ---- radix CSR build: zero global atomics ----
    bucket_hist_kernel<<<NBLK, 256, 0, stream>>>(dst, bcnt, E, EPB, NBLK);
    scan1_kernel<<<NB2, 256, 0, stream>>>(bcnt, bofs, bsum);
    scan2_kernel<<<1, NB2, NB2 * sizeof(int), stream>>>(bsum, NB2);
    scan3_kernel<<<NB2, 256, 0, stream>>>(bofs, bsum);
    partition_kernel<<<NBLK, 256, 0, stream>>>(src, dst, bofs, part, E, EPB, NBLK);
    local_csr_kernel<<<NBUCKET, 256, 0, stream>>>(bofs, part, row_ptr, csr_src, N, E, NBLK);

    // ---- h0 = x @ W_lin + b_lin (fp16 out) ----
    lin16_kernel<<<(N + BLK - 1) / BLK, BLK, 0, stream>>>(x, W_lin, b_lin, h0, N);

    // ---- block3: 16 -> 32, relu (fused fp16 gather + MFMA) ----
    fused_kernel<16, 32, 0, true, true, false><<<N / 64, 256, 0, stream>>>(
        h0, nullptr, row_ptr, csr_src, Wt3, b3, nullptr, gmax + 0, h3, N);

    // ---- block2: 32 -> 64, relu (u8 quant + fused gather + MFMA) ----
    quant_kernel<<<(N * 32 / 16 + BLK - 1) / BLK, BLK, 0, stream>>>(h3, gmax + 0, h3q, N * 32 / 16);
    fused_kernel<32, 64, 0, true, true, true><<<N / 64, 256, 0, stream>>>(
        h3, h3q, row_ptr, csr_src, Wt2, b2, gmax + 0, gmax + 1, h2, N);

    // ---- block1: 64 -> 128, sigmoid -> d_out fp32 (u8 quant + fused) ----
    quant_kernel<<<(N * 64 / 16 + BLK - 1) / BLK, BLK, 0, stream>>>(h2, gmax + 1, h2q, N * 64 / 16);
    fused_kernel<64, 128, 1, false, false, true><<<N / 64, 256, 0, stream>>>(
        h2, h2q, row_ptr, csr_src, Wt1, b1, gmax + 1, nullptr, out, N);
}

// Round 6
// 317.077 us; speedup vs baseline: 1.1799x; 1.1799x over previous
//
#include <hip/hip_runtime.h>
#include <cmath>

// ---------------------------------------------------------------------------
// Decoder_1898375544952: STGCN decoder (radix CSR + fp16 gather + MFMA GEMM)
//   h0 = x @ W_lin + b_lin                         [N,16]
//   h3 = relu(h0 @ Ws3 + mean_agg(h0) @ Wn3 + b3)  [N,32]
//   h2 = relu(h3 @ Ws2 + mean_agg(h3) @ Wn2 + b2)  [N,64]
//   out= sigm(h2 @ Ws1 + mean_agg(h2) @ Wn1 + b1)  [N,128]
//
// R9 radix CSR -> 377us. R10 fp16 MFMA -> 339us. R11 8-wide gather -> 336.7
//   (BEST). R12 chunking -> 379 (32B misses + launch overhead). R13
//   phase-sort -> 343 (no L2 phasing materialized). R14 u8 quant gather ->
//   354 (gathers faster but NT agg stores forced HBM round-trip + extra
//   passes). R15 fused gather+GEMM -> 374 (44KB LDS -> 26% occupancy killed
//   gather TLP; MfmaUtil 2%).
// R16: revert to R11 exactly; change ONLY the dispatch with unambiguous
//   counter-proven waste: partition_kernel (43us, 1.5TB/s, VALUBusy 0.9%,
//   WRITE 50MB vs 16 ideal = 3.3x sector amplification).
//   (a) pack part entries u32 = (src<<8)|(dst&255)  -> half payload;
//   (b) NBLK 512->256 -> ~64B per-bucket runs -> full sectors;
//   (c) merge 3 wt launches into 1 (pure launch overhead).
//   Gather/GEMM/lin16 byte-identical to R11 (controls).
// ---------------------------------------------------------------------------

typedef __attribute__((ext_vector_type(8))) _Float16 half8;
typedef __attribute__((ext_vector_type(4))) float floatx4;

#define NBUCKET 512
#define BUCKET_SHIFT 8   // 256 nodes per bucket; N = 131072 = 512*256

// ---- Pass A: per-block bucket histogram (LDS atomics only) ----
__global__ __launch_bounds__(256) void bucket_hist_kernel(
    const int* __restrict__ dst, int* __restrict__ bcnt, int E, int EPB, int nblk) {
    __shared__ int lh[NBUCKET];
    for (int i = threadIdx.x; i < NBUCKET; i += 256) lh[i] = 0;
    __syncthreads();
    int base = blockIdx.x * EPB;
    int end  = min(base + EPB, E);
    for (int i = base + threadIdx.x; i < end; i += 256)
        atomicAdd(&lh[dst[i] >> BUCKET_SHIFT], 1);
    __syncthreads();
    for (int i = threadIdx.x; i < NBUCKET; i += 256)
        bcnt[i * nblk + blockIdx.x] = lh[i];        // bucket-major
}

// ---- scan helpers ----
__global__ void scan1_kernel(const int* __restrict__ in, int* __restrict__ out,
                             int* __restrict__ bsum) {
    __shared__ int s[256];
    int i = blockIdx.x * 256 + threadIdx.x;
    int v = in[i];
    s[threadIdx.x] = v;
    __syncthreads();
    for (int off = 1; off < 256; off <<= 1) {
        int t = (threadIdx.x >= off) ? s[threadIdx.x - off] : 0;
        __syncthreads();
        s[threadIdx.x] += t;
        __syncthreads();
    }
    out[i] = s[threadIdx.x] - v;
    if (threadIdx.x == 255) bsum[blockIdx.x] = s[255];
}

__global__ void scan2_kernel(int* __restrict__ bsum, int NB) {
    extern __shared__ int s2[];
    int v = (threadIdx.x < NB) ? bsum[threadIdx.x] : 0;
    s2[threadIdx.x] = v;
    __syncthreads();
    for (int off = 1; off < NB; off <<= 1) {
        int t = (threadIdx.x >= off) ? s2[threadIdx.x - off] : 0;
        __syncthreads();
        s2[threadIdx.x] += t;
        __syncthreads();
    }
    if (threadIdx.x < NB) bsum[threadIdx.x] = s2[threadIdx.x] - v;
}

__global__ void scan3_kernel(int* __restrict__ out, const int* __restrict__ bsum) {
    int i = blockIdx.x * 256 + threadIdx.x;
    out[i] += bsum[blockIdx.x];
}

// ---- Pass C: partition edges into bucket segments (LDS cursors) ----
// Packed entry: (src << 8) | (dst & 255). src < 2^24, bucket-local dst 8b.
__global__ __launch_bounds__(256) void partition_kernel(
    const int* __restrict__ src, const int* __restrict__ dst,
    const int* __restrict__ bofs, int* __restrict__ part,
    int E, int EPB, int nblk) {
    __shared__ int cur[NBUCKET];
    for (int i = threadIdx.x; i < NBUCKET; i += 256)
        cur[i] = bofs[i * nblk + blockIdx.x];
    __syncthreads();
    int base = blockIdx.x * EPB;
    int end  = min(base + EPB, E);
    for (int i = base + threadIdx.x; i < end; i += 256) {
        int d = dst[i];
        int p = atomicAdd(&cur[d >> BUCKET_SHIFT], 1);
        part[p] = (src[i] << 8) | (d & 255);
    }
}

// ---- Pass D: per-bucket local CSR (row_ptr + csr_src), all LDS-local ----
__global__ __launch_bounds__(256) void local_csr_kernel(
    const int* __restrict__ bofs, const int* __restrict__ part,
    int* __restrict__ row_ptr, int* __restrict__ csr_src,
    int N, int E, int nblk) {
    __shared__ int cnt[256];
    __shared__ int offs[256];
    const int u      = blockIdx.x;
    const int node0  = u << BUCKET_SHIFT;
    const int bstart = bofs[(size_t)u * nblk];
    const int bend   = (u + 1 < gridDim.x) ? bofs[(size_t)(u + 1) * nblk] : E;

    cnt[threadIdx.x] = 0;
    __syncthreads();
    for (int i = bstart + threadIdx.x; i < bend; i += 256)
        atomicAdd(&cnt[part[i] & 255], 1);
    __syncthreads();

    int v = cnt[threadIdx.x];
    offs[threadIdx.x] = v;
    __syncthreads();
    for (int off = 1; off < 256; off <<= 1) {
        int t = (threadIdx.x >= off) ? offs[threadIdx.x - off] : 0;
        __syncthreads();
        offs[threadIdx.x] += t;
        __syncthreads();
    }
    int excl = offs[threadIdx.x] - v;
    int rbase = bstart + excl;
    if (node0 + threadIdx.x < N) row_ptr[node0 + threadIdx.x] = rbase;
    if (u == 0 && threadIdx.x == 0) row_ptr[N] = E;
    __syncthreads();
    cnt[threadIdx.x] = rbase;       // reuse as cursor
    __syncthreads();
    for (int i = bstart + threadIdx.x; i < bend; i += 256) {
        int e = part[i];
        int p = atomicAdd(&cnt[e & 255], 1);
        csr_src[p] = e >> 8;
    }
}

// ---- merged weight transpose+concat for all 3 layers (1 launch) ----
// Wt[n][k] = (k<CI ? Ws[k][n] : Wn[k-CI][n]) as fp16.
__global__ void wt_all_kernel(
    const float* __restrict__ Ws1, const float* __restrict__ Wn1, _Float16* __restrict__ Wt1,
    const float* __restrict__ Ws2, const float* __restrict__ Wn2, _Float16* __restrict__ Wt2,
    const float* __restrict__ Ws3, const float* __restrict__ Wn3, _Float16* __restrict__ Wt3) {
    int idx = blockIdx.x * 256 + threadIdx.x;
    const float *Ws, *Wn; _Float16* Wt; int CI, NOUT;
    if (idx < 16384)        { Ws = Ws1; Wn = Wn1; Wt = Wt1; CI = 64; NOUT = 128; }
    else if (idx < 20480)   { idx -= 16384; Ws = Ws2; Wn = Wn2; Wt = Wt2; CI = 32; NOUT = 64; }
    else if (idx < 21504)   { idx -= 20480; Ws = Ws3; Wn = Wn3; Wt = Wt3; CI = 16; NOUT = 32; }
    else return;
    int K = 2 * CI;
    int n = idx / K, k = idx - n * K;
    float v = (k < CI) ? Ws[(size_t)k * NOUT + n] : Wn[(size_t)(k - CI) * NOUT + n];
    Wt[n * K + k] = (_Float16)v;
}

// h0 = x @ W (16x16) + b, stored fp16
__global__ void lin16_kernel(const float* __restrict__ x, const float* __restrict__ W,
                             const float* __restrict__ b, _Float16* __restrict__ h, int N) {
    __shared__ float sW[256];
    __shared__ float sb[16];
    sW[threadIdx.x] = W[threadIdx.x];          // blockDim.x == 256
    if (threadIdx.x < 16) sb[threadIdx.x] = b[threadIdx.x];
    __syncthreads();
    int n = blockIdx.x * blockDim.x + threadIdx.x;
    if (n >= N) return;
    const float4* xr = (const float4*)(x + (size_t)n * 16);
    float4 x0 = xr[0], x1 = xr[1], x2 = xr[2], x3 = xr[3];
    float xi[16] = {x0.x, x0.y, x0.z, x0.w, x1.x, x1.y, x1.z, x1.w,
                    x2.x, x2.y, x2.z, x2.w, x3.x, x3.y, x3.z, x3.w};
    float o[16];
#pragma unroll
    for (int j = 0; j < 16; j++) o[j] = sb[j];
#pragma unroll
    for (int k = 0; k < 16; k++) {
        float xv = xi[k];
#pragma unroll
        for (int j = 0; j < 16; j++) o[j] += xv * sW[k * 16 + j];
    }
    half8 h0v, h1v;
#pragma unroll
    for (int j = 0; j < 8; j++) { h0v[j] = (_Float16)o[j]; h1v[j] = (_Float16)o[j + 8]; }
    half8* hr = (half8*)(h + (size_t)n * 16);
    hr[0] = h0v;
    hr[1] = h1v;
}

// agg[n][g*8..] = (1/max(deg,1)) * sum over CSR neighbors of h[src][g*8..]
// R11 form: 8-wide unrolled rounds + single masked tail round. (BEST: 336.7)
template <int C>
__global__ __launch_bounds__(256) void gather_kernel(
    const int* __restrict__ row_ptr, const int* __restrict__ csr_src,
    const _Float16* __restrict__ h, _Float16* __restrict__ agg, int N) {
    constexpr int GP = C / 8;
    int t = blockIdx.x * blockDim.x + threadIdx.x;
    int total = N * GP;
    if (t >= total) return;
    int n = t / GP;
    int g = t - n * GP;
    const int beg = row_ptr[n];
    const int end = row_ptr[n + 1];
    const size_t goff = (size_t)g * 8;

    float a0[8], a1[8];
#pragma unroll
    for (int i = 0; i < 8; i++) { a0[i] = 0.f; a1[i] = 0.f; }

    int j = beg;
    // main: full 8-wide rounds, no masking
    for (; j + 8 <= end; j += 8) {
        int i0 = csr_src[j + 0], i1 = csr_src[j + 1], i2 = csr_src[j + 2], i3 = csr_src[j + 3];
        int i4 = csr_src[j + 4], i5 = csr_src[j + 5], i6 = csr_src[j + 6], i7 = csr_src[j + 7];
        half8 v0 = *(const half8*)(h + (size_t)i0 * C + goff);
        half8 v1 = *(const half8*)(h + (size_t)i1 * C + goff);
        half8 v2 = *(const half8*)(h + (size_t)i2 * C + goff);
        half8 v3 = *(const half8*)(h + (size_t)i3 * C + goff);
        half8 v4 = *(const half8*)(h + (size_t)i4 * C + goff);
        half8 v5 = *(const half8*)(h + (size_t)i5 * C + goff);
        half8 v6 = *(const half8*)(h + (size_t)i6 * C + goff);
        half8 v7 = *(const half8*)(h + (size_t)i7 * C + goff);
#pragma unroll
        for (int i = 0; i < 8; i++) {
            a0[i] += ((float)v0[i] + (float)v2[i]) + ((float)v4[i] + (float)v6[i]);
            a1[i] += ((float)v1[i] + (float)v3[i]) + ((float)v5[i] + (float)v7[i]);
        }
    }
    // tail: one masked 8-wide round (clamped index, 0/1 weight)
    if (j < end) {
        const int last = end - 1;
        int i0 = csr_src[j];
        int i1 = csr_src[min(j + 1, last)];
        int i2 = csr_src[min(j + 2, last)];
        int i3 = csr_src[min(j + 3, last)];
        int i4 = csr_src[min(j + 4, last)];
        int i5 = csr_src[min(j + 5, last)];
        int i6 = csr_src[min(j + 6, last)];
        int i7 = csr_src[min(j + 7, last)];
        half8 v0 = *(const half8*)(h + (size_t)i0 * C + goff);
        half8 v1 = *(const half8*)(h + (size_t)i1 * C + goff);
        half8 v2 = *(const half8*)(h + (size_t)i2 * C + goff);
        half8 v3 = *(const half8*)(h + (size_t)i3 * C + goff);
        half8 v4 = *(const half8*)(h + (size_t)i4 * C + goff);
        half8 v5 = *(const half8*)(h + (size_t)i5 * C + goff);
        half8 v6 = *(const half8*)(h + (size_t)i6 * C + goff);
        half8 v7 = *(const half8*)(h + (size_t)i7 * C + goff);
        float w1 = (j + 1 < end) ? 1.f : 0.f;
        float w2 = (j + 2 < end) ? 1.f : 0.f;
        float w3 = (j + 3 < end) ? 1.f : 0.f;
        float w4 = (j + 4 < end) ? 1.f : 0.f;
        float w5 = (j + 5 < end) ? 1.f : 0.f;
        float w6 = (j + 6 < end) ? 1.f : 0.f;
        float w7 = (j + 7 < end) ? 1.f : 0.f;
#pragma unroll
        for (int i = 0; i < 8; i++) {
            a0[i] += ((float)v0[i] + w2 * (float)v2[i]) + (w4 * (float)v4[i] + w6 * (float)v6[i]);
            a1[i] += (w1 * (float)v1[i] + w3 * (float)v3[i]) + (w5 * (float)v5[i] + w7 * (float)v7[i]);
        }
    }

    float inv = 1.0f / fmaxf((float)(end - beg), 1.0f);
    half8 r;
#pragma unroll
    for (int i = 0; i < 8; i++) r[i] = (_Float16)((a0[i] + a1[i]) * inv);
    *(half8*)(agg + (size_t)n * C + goff) = r;
}

// ---- MFMA GEMM: out = act([h | a] @ Wt^T + b) with Wt[n][K] fp16 ----
// Block = 256 threads = 4 waves; wave w handles rows blockIdx.x*64 + w*16 .. +16.
// A-frag: lane m=lane&15, quad=lane>>4 reads h/a[row][s*32+quad*8 .. +8].
// B-frag: lane reads Bt[c*16+m][s*32+quad*8 .. +8] from padded LDS.
// C/D: col = c*16 + (lane&15), row = row0 + quad*4 + reg.
// ACT: 0 relu, 1 sigmoid. OUT_F16: fp16 vs fp32 output.
template <int CI, int NOUT, int ACT, bool OUT_F16>
__global__ __launch_bounds__(256) void mfma_gemm_kernel(
    const _Float16* __restrict__ hbuf, const _Float16* __restrict__ abuf,
    const _Float16* __restrict__ Wt,   // [NOUT][K] fp16
    const float* __restrict__ bias, void* __restrict__ outp, int N)
{
    constexpr int K   = 2 * CI;
    constexpr int KS  = K / 32;        // k-steps (4/2/1)
    constexpr int CT  = NOUT / 16;     // col tiles (8/4/2)
    constexpr int LDW = K + 8;         // padded LDS row (halves); LDW*2 % 16 == 0
    __shared__ _Float16 Bt[NOUT * LDW];

    const int tid = threadIdx.x;
    // stage Wt -> LDS (half8 copies)
    for (int idx = tid; idx < NOUT * (K / 8); idx += 256) {
        int n  = idx / (K / 8);
        int kq = idx - n * (K / 8);
        *(half8*)&Bt[n * LDW + kq * 8] = *(const half8*)(Wt + (size_t)n * K + kq * 8);
    }
    __syncthreads();

    const int wave = tid >> 6;
    const int lane = tid & 63;
    const int m    = lane & 15;
    const int quad = lane >> 4;
    const int row0 = blockIdx.x * 64 + wave * 16;
    const size_t row = (size_t)(row0 + m);

    floatx4 acc[CT];
#pragma unroll
    for (int c = 0; c < CT; c++) acc[c] = (floatx4){0.f, 0.f, 0.f, 0.f};

#pragma unroll
    for (int s = 0; s < KS; s++) {
        int k8 = s * 32 + quad * 8;
        const _Float16* Ap = (k8 < CI) ? (hbuf + row * CI + k8)
                                       : (abuf + row * CI + (k8 - CI));
        half8 a = *(const half8*)Ap;
#pragma unroll
        for (int c = 0; c < CT; c++) {
            half8 b = *(const half8*)&Bt[(c * 16 + m) * LDW + k8];
            acc[c] = __builtin_amdgcn_mfma_f32_16x16x32_f16(a, b, acc[c], 0, 0, 0);
        }
    }

    // epilogue
#pragma unroll
    for (int c = 0; c < CT; c++) {
        int col = c * 16 + m;
        float bv = bias[col];
#pragma unroll
        for (int j = 0; j < 4; j++) {
            int orow = row0 + quad * 4 + j;
            float v = acc[c][j] + bv;
            if (ACT == 0) v = fmaxf(v, 0.0f);
            else          v = 1.0f / (1.0f + __expf(-v));
            if (OUT_F16) ((_Float16*)outp)[(size_t)orow * NOUT + col] = (_Float16)v;
            else         ((float*)outp)[(size_t)orow * NOUT + col] = v;
        }
    }
}

extern "C" void kernel_launch(void* const* d_in, const int* in_sizes, int n_in,
                              void* d_out, int out_size, void* d_ws, size_t ws_size,
                              hipStream_t stream) {
    const float* x     = (const float*)d_in[0];
    const int*   ei    = (const int*)d_in[1];
    // d_in[2]: batch (unused)
    const float* W_lin = (const float*)d_in[3];
    const float* b_lin = (const float*)d_in[4];
    const float* Ws3   = (const float*)d_in[5];
    const float* Wn3   = (const float*)d_in[6];
    const float* b3    = (const float*)d_in[7];
    const float* Ws2   = (const float*)d_in[8];
    const float* Wn2   = (const float*)d_in[9];
    const float* b2    = (const float*)d_in[10];
    const float* Ws1   = (const float*)d_in[11];
    const float* Wn1   = (const float*)d_in[12];
    const float* b1    = (const float*)d_in[13];
    float* out = (float*)d_out;

    const int N = in_sizes[0] / 16;
    const int E = in_sizes[1] / 2;
    const int* src = ei;
    const int* dst = ei + E;

    const int NBLK = 256;                       // partition blocks (~64B runs)
    const int EPB  = (E + NBLK - 1) / NBLK;
    const int M    = NBUCKET * NBLK;            // 131072 count entries
    const int NB2  = M / 256;                   // 512

    // Workspace (ints unless noted).
    int* wsi = (int*)d_ws;
    int* row_ptr = wsi;
    size_t B0 = ((size_t)(N + 1) + 3) & ~(size_t)3;
    int* bcnt = wsi + B0;
    int* bofs = bcnt + M;
    int* bsum = bofs + M;
    size_t C0 = (B0 + 2 * (size_t)M + (size_t)NB2 + 3) & ~(size_t)3;
    int* csr_src = wsi + C0;
    size_t P0 = (C0 + (size_t)E + 3) & ~(size_t)3;
    int* part = wsi + P0;                       // E packed u32
    size_t H0 = (P0 + (size_t)E + 3) & ~(size_t)3;
    _Float16* regA = (_Float16*)(wsi + H0);
    _Float16* regB = regA + (size_t)64 * N;
    _Float16* Wt1  = regB + (size_t)64 * N;     // 128*128 = 16384 halves
    _Float16* Wt2  = Wt1 + 16384;               // 64*64   = 4096
    _Float16* Wt3  = Wt2 + 4096;                // 32*32   = 1024

    _Float16* h0    = regA;
    _Float16* agg16 = regA + (size_t)16 * N;
    _Float16* h2    = regA;                    // after h0/agg16 dead
    _Float16* h3    = regB;
    _Float16* agg32 = regB + (size_t)32 * N;
    _Float16* agg64 = regB;                    // after h3/agg32 dead

    const int BLK = 256;

    // ---- weight transposes (1 merged launch) ----
    wt_all_kernel<<<(21504 + 255) / 256, 256, 0, stream>>>(
        Ws1, Wn1, Wt1, Ws2, Wn2, Wt2, Ws3, Wn3, Wt3);

    // ---- radix CSR build: zero global atomics ----
    bucket_hist_kernel<<<NBLK, 256, 0, stream>>>(dst, bcnt, E, EPB, NBLK);
    scan1_kernel<<<NB2, 256, 0, stream>>>(bcnt, bofs, bsum);
    scan2_kernel<<<1, NB2, NB2 * sizeof(int), stream>>>(bsum, NB2);
    scan3_kernel<<<NB2, 256, 0, stream>>>(bofs, bsum);
    partition_kernel<<<NBLK, 256, 0, stream>>>(src, dst, bofs, part, E, EPB, NBLK);
    local_csr_kernel<<<NBUCKET, 256, 0, stream>>>(bofs, part, row_ptr, csr_src, N, E, NBLK);

    // ---- h0 = x @ W_lin + b_lin (fp16 out) ----
    lin16_kernel<<<(N + BLK - 1) / BLK, BLK, 0, stream>>>(x, W_lin, b_lin, h0, N);

    // ---- block3: 16 -> 32, relu ----
    gather_kernel<16><<<((size_t)N * 2 + BLK - 1) / BLK, BLK, 0, stream>>>(row_ptr, csr_src, h0, agg16, N);
    mfma_gemm_kernel<16, 32, 0, true><<<N / 64, 256, 0, stream>>>(h0, agg16, Wt3, b3, h3, N);

    // ---- block2: 32 -> 64, relu ----
    gather_kernel<32><<<((size_t)N * 4 + BLK - 1) / BLK, BLK, 0, stream>>>(row_ptr, csr_src, h3, agg32, N);
    mfma_gemm_kernel<32, 64, 0, true><<<N / 64, 256, 0, stream>>>(h3, agg32, Wt2, b2, h2, N);

    // ---- block1: 64 -> 128, sigmoid -> d_out (fp32) ----
    gather_kernel<64><<<((size_t)N * 8 + BLK - 1) / BLK, BLK, 0, stream>>>(row_ptr, csr_src, h2, agg64, N);
    mfma_gemm_kernel<64, 128, 1, false><<<N / 64, 256, 0, stream>>>(h2, agg64, Wt1, b1, out, N);
}